// Round 10
// baseline (75.068 us; speedup 1.0000x reference)
//
#include <hip/hip_runtime.h>
#include <math.h>

// Problem constants (fixed by setup_inputs)
constexpr int B       = 2;
constexpr int N       = 32768;
constexpr int D       = 3;
constexpr int M_FULL  = 8192;
constexpr int SUBDIV  = 8;
constexpr int M       = M_FULL / SUBDIV;   // 1024 subsampled verts per (b,d)
constexpr int K       = 512;               // value buckets over [-4,4]
constexpr float LO    = -4.0f;
constexpr float INV_W = 64.0f;             // 1 / (8/512)
constexpr int BLOCK   = 1024;
constexpr int QBLK    = 512;               // queries per block
constexpr int CHUNKS  = N / QBLK;          // 64 blocks per (b,d) pair
constexpr int GRID    = B * D * CHUNKS;    // 384 blocks -> 2 per CU (32 waves/CU, max)
constexpr float K4    = 5.770780163555852f; // 4*log2(e): e^{4t} = 2^{K4*t}

// ---- 512-element wave-parallel scans (one wave, lane owns 8 slots) ----
__device__ inline void scan512_pre(float* a) {   // exclusive prefix, small-first
    const int lane = threadIdx.x & 63;
    const int base = lane * 8;
    float xv[8], e[8]; float ls = 0.f;
    #pragma unroll
    for (int t = 0; t < 8; ++t) xv[t] = a[base + t];
    #pragma unroll
    for (int t = 0; t < 8; ++t) { e[t] = ls; ls += xv[t]; }
    float inc = ls;
    #pragma unroll
    for (int off = 1; off < 64; off <<= 1) {
        const float tmp = __shfl_up(inc, off, 64);
        if (lane >= off) inc += tmp;
    }
    const float exoff = inc - ls;
    #pragma unroll
    for (int t = 0; t < 8; ++t) a[base + t] = exoff + e[t];
}

__device__ inline void scan512_suf(float* a) {   // inclusive suffix, small-first
    const int lane = threadIdx.x & 63;
    const int base = lane * 8;
    float xv[8], e[8]; float ls = 0.f;
    #pragma unroll
    for (int t = 0; t < 8; ++t) xv[t] = a[base + t];
    #pragma unroll
    for (int t = 7; t >= 0; --t) { e[t] = ls; ls += xv[t]; }
    float inc = ls;
    #pragma unroll
    for (int off = 1; off < 64; off <<= 1) {
        const float tmp = __shfl_down(inc, off, 64);
        if (lane + off < 64) inc += tmp;
    }
    const float exoff = inc - ls;
    #pragma unroll
    for (int t = 0; t < 8; ++t) a[base + t] = exoff + e[t] + xv[t];
}

__device__ inline void scan512_beg(const int* cntA, int* begA) {  // exclusive
    const int lane = threadIdx.x & 63;
    const int base = lane * 8;
    int xv[8], e[8]; int ls = 0;
    #pragma unroll
    for (int t = 0; t < 8; ++t) xv[t] = cntA[base + t];
    #pragma unroll
    for (int t = 0; t < 8; ++t) { e[t] = ls; ls += xv[t]; }
    int inc = ls;
    #pragma unroll
    for (int off = 1; off < 64; off <<= 1) {
        const int tmp = __shfl_up(inc, off, 64);
        if (lane >= off) inc += tmp;
    }
    const int exoff = inc - ls;
    #pragma unroll
    for (int t = 0; t < 8; ++t) begA[base + t] = exoff + e[t];
}

__global__ __launch_bounds__(BLOCK) void deformer_one(
    const float* __restrict__ x,
    const float* __restrict__ dverts,
    const float* __restrict__ mverts,
    float* __restrict__ out)
{
    // bucket-grouped per-vert tuples
    __shared__ float sV[M], sAp[M], sSp[M], sAm[M], sSm[M];      // 20 KB
    // per-bucket aggregates; after scans: Ap/Sp = exclusive prefix,
    // Am/Sm = inclusive suffix (both accumulated tiny-terms-first).
    __shared__ float gAp[K], gSp[K], gAm[K], gSm[K];             // 8 KB
    __shared__ int   cnt[K], beg[K];                              // 4 KB

    const int tid = threadIdx.x;
    const int p = blockIdx.x >> 6;    // pair 0..5
    const int c = blockIdx.x & 63;    // chunk within pair
    const int b = p / 3, d = p % 3;

    // ---- Issue ALL global loads up front (dv, mv, x independent) ----
    const int g = (b * M_FULL + tid * SUBDIV) * D + d;
    const float v = dverts[g];
    const float w = mverts[g];
    const int n = c * QBLK + (tid & (QBLK - 1));
    const int o = (b * N + n) * D + d;
    const float xq = x[o];            // query input prefetched under build

    // zero-init overlaps the load drain
    if (tid < K) {
        cnt[tid] = 0; gAp[tid] = 0.f; gSp[tid] = 0.f;
        gAm[tid] = 0.f; gSm[tid] = 0.f;
    }

    // per-vert terms (stall on v/w here, not earlier)
    const float epv = __builtin_amdgcn_exp2f( K4 * v);   // e^{4v}
    const float emv = __builtin_amdgcn_exp2f(-K4 * v);   // e^{-4v}
    const float ap = w * epv, sp = epv;
    const float am = w * emv, sm = emv;
    int bj = (int)floorf((v - LO) * INV_W);
    bj = bj < 0 ? 0 : (bj > K - 1 ? K - 1 : bj);
    __syncthreads();                  // zero-init visible

    // rank captured from the cnt atomic: in-bucket slot, no second atomic pass
    const int rank = atomicAdd(&cnt[bj], 1);
    atomicAdd(&gAp[bj], ap);
    atomicAdd(&gSp[bj], sp);
    atomicAdd(&gAm[bj], am);
    atomicAdd(&gSm[bj], sm);
    __syncthreads();

    // Scans: 5 scans on 5 separate waves, concurrent (waves 5-15 fall through).
    const int wid = tid >> 6;
    if      (wid == 0) scan512_beg(cnt, beg);
    else if (wid == 1) scan512_pre(gAp);
    else if (wid == 2) scan512_pre(gSp);
    else if (wid == 3) scan512_suf(gAm);
    else if (wid == 4) scan512_suf(gSm);
    __syncthreads();

    // Scatter into bucket-grouped order at precomputed slot.
    const int pos = beg[bj] + rank;
    sV[pos] = v; sAp[pos] = ap; sSp[pos] = sp;
    sAm[pos] = am; sSm[pos] = sm;
    __syncthreads();

    // ---- Query: threads 0..QBLK-1 each produce one output element ----
    if (tid < QBLK) {
        int j = (int)floorf((xq - LO) * INV_W);
        j = j < 0 ? 0 : (j > K - 1 ? K - 1 : j);

        const float en  = __builtin_amdgcn_exp2f(-K4 * xq);  // e^{-4x}
        const float epx = __builtin_amdgcn_exp2f( K4 * xq);  // e^{+4x}

        const float Ap = gAp[j];                          // buckets strictly below j
        const float Sp = gSp[j];
        const float Am = (j < K - 1) ? gAm[j + 1] : 0.f;  // buckets strictly above j
        const float Sm = (j < K - 1) ? gSm[j + 1] : 0.f;

        const int s0 = beg[j], s1 = s0 + cnt[j];
        float rAp = 0.f, rSp = 0.f, rAm = 0.f, rSm = 0.f;
        for (int i = s0; i < s1; ++i) {
            const bool le = (sV[i] <= xq);
            rAp += le ? sAp[i] : 0.f;
            rSp += le ? sSp[i] : 0.f;
            rAm += le ? 0.f : sAm[i];
            rSm += le ? 0.f : sSm[i];
        }
        out[o] = (en * (Ap + rAp) + epx * (Am + rAm)) /
                 (en * (Sp + rSp) + epx * (Sm + rSm));
    }
}

extern "C" void kernel_launch(void* const* d_in, const int* in_sizes, int n_in,
                              void* d_out, int out_size, void* d_ws, size_t ws_size,
                              hipStream_t stream) {
    const float* x  = (const float*)d_in[0];
    const float* dv = (const float*)d_in[1];
    const float* mv = (const float*)d_in[2];
    float* out = (float*)d_out;

    deformer_one<<<GRID, BLOCK, 0, stream>>>(x, dv, mv, out);
}

// Round 11
// 71.717 us; speedup vs baseline: 1.0467x; 1.0467x over previous
//
#include <hip/hip_runtime.h>
#include <math.h>

// Problem constants (fixed by setup_inputs)
constexpr int B       = 2;
constexpr int N       = 32768;
constexpr int D       = 3;
constexpr int M_FULL  = 8192;
constexpr int SUBDIV  = 8;
constexpr int M       = M_FULL / SUBDIV;   // 1024 subsampled verts per (b,d)
constexpr int K       = 512;               // value buckets over [-4,4]
constexpr float LO    = -4.0f;
constexpr float INV_W = 64.0f;             // 1 / (8/512)
constexpr int BLOCK   = 1024;              // 16 waves/CU
constexpr int CHUNKS  = N / BLOCK;         // 32 blocks per (b,d) pair
constexpr int GRID    = B * D * CHUNKS;    // 192 blocks -> 1 per CU
constexpr int BF4     = M_FULL * D / 4;    // 6144 float4 per batch region
constexpr float K4    = 5.770780163555852f; // 4*log2(e): e^{4t} = 2^{K4*t}

// ---- 512-element wave-parallel scans (one wave, lane owns 8 slots) ----
__device__ inline void scan512_pre(float* a) {   // exclusive prefix, small-first
    const int lane = threadIdx.x & 63;
    const int base = lane * 8;
    float xv[8], e[8]; float ls = 0.f;
    #pragma unroll
    for (int t = 0; t < 8; ++t) xv[t] = a[base + t];
    #pragma unroll
    for (int t = 0; t < 8; ++t) { e[t] = ls; ls += xv[t]; }
    float inc = ls;
    #pragma unroll
    for (int off = 1; off < 64; off <<= 1) {
        const float tmp = __shfl_up(inc, off, 64);
        if (lane >= off) inc += tmp;
    }
    const float exoff = inc - ls;
    #pragma unroll
    for (int t = 0; t < 8; ++t) a[base + t] = exoff + e[t];
}

__device__ inline void scan512_suf(float* a) {   // inclusive suffix, small-first
    const int lane = threadIdx.x & 63;
    const int base = lane * 8;
    float xv[8], e[8]; float ls = 0.f;
    #pragma unroll
    for (int t = 0; t < 8; ++t) xv[t] = a[base + t];
    #pragma unroll
    for (int t = 7; t >= 0; --t) { e[t] = ls; ls += xv[t]; }
    float inc = ls;
    #pragma unroll
    for (int off = 1; off < 64; off <<= 1) {
        const float tmp = __shfl_down(inc, off, 64);
        if (lane + off < 64) inc += tmp;
    }
    const float exoff = inc - ls;
    #pragma unroll
    for (int t = 0; t < 8; ++t) a[base + t] = exoff + e[t] + xv[t];
}

__device__ inline void scan512_beg(const int* cntA, int* begA) {  // exclusive
    const int lane = threadIdx.x & 63;
    const int base = lane * 8;
    int xv[8], e[8]; int ls = 0;
    #pragma unroll
    for (int t = 0; t < 8; ++t) xv[t] = cntA[base + t];
    #pragma unroll
    for (int t = 0; t < 8; ++t) { e[t] = ls; ls += xv[t]; }
    int inc = ls;
    #pragma unroll
    for (int off = 1; off < 64; off <<= 1) {
        const int tmp = __shfl_up(inc, off, 64);
        if (lane >= off) inc += tmp;
    }
    const int exoff = inc - ls;
    #pragma unroll
    for (int t = 0; t < 8; ++t) begA[base + t] = exoff + e[t];
}

__global__ __launch_bounds__(BLOCK) void deformer_one(
    const float* __restrict__ x,
    const float* __restrict__ dverts,
    const float* __restrict__ mverts,
    float* __restrict__ out)
{
    // bucket-grouped per-vert tuples
    __shared__ float sV[M], sAp[M], sSp[M], sAm[M], sSm[M];      // 20 KB
    // per-bucket aggregates; after scans: Ap/Sp = exclusive prefix,
    // Am/Sm = inclusive suffix (both accumulated tiny-terms-first).
    __shared__ float gAp[K], gSp[K], gAm[K], gSm[K];             // 8 KB
    __shared__ int   cnt[K], beg[K];                              // 4 KB
    // coalesced-gather staging: subsampled verts in natural order
    __shared__ float sRawV[M], sRawW[M];                          // 8 KB

    const int tid = threadIdx.x;
    const int p = blockIdx.x >> 5;    // pair 0..5
    const int c = blockIdx.x & 31;    // chunk within pair
    const int b = p / 3, d = p % 3;

    // ---- query-input load issued up front ----
    const int n = c * BLOCK + tid;
    const int o = (b * N + n) * D + d;
    const float xq = x[o];

    // ---- COALESCED gather of the batch's vert region via LDS redistribute ----
    // float4 index q in [0,6144) holds floats 4q..4q+3 of the batch region.
    // Subsampled vert m (stride 24 floats) component d sits at float 24m+d,
    // i.e. in float4 q=6m, component d.  q%6==0 -> useful.
    {
        const float4* dv4 = reinterpret_cast<const float4*>(dverts) + b * BF4;
        const float4* mv4 = reinterpret_cast<const float4*>(mverts) + b * BF4;
        #pragma unroll
        for (int k = 0; k < 6; ++k) {
            const int q = tid + k * BLOCK;
            const float4 a = dv4[q];
            if (q % 6 == 0)
                sRawV[q / 6] = (d == 0) ? a.x : ((d == 1) ? a.y : a.z);
        }
        #pragma unroll
        for (int k = 0; k < 6; ++k) {
            const int q = tid + k * BLOCK;
            const float4 a = mv4[q];
            if (q % 6 == 0)
                sRawW[q / 6] = (d == 0) ? a.x : ((d == 1) ? a.y : a.z);
        }
    }

    // zero-init overlaps the gather drain
    if (tid < K) {
        cnt[tid] = 0; gAp[tid] = 0.f; gSp[tid] = 0.f;
        gAm[tid] = 0.f; gSm[tid] = 0.f;
    }
    __syncthreads();   // raw verts + zero-init visible

    // ---- per-vert terms: one vert per thread, from LDS ----
    const float v = sRawV[tid];
    const float w = sRawW[tid];
    const float epv = __builtin_amdgcn_exp2f( K4 * v);   // e^{4v}
    const float emv = __builtin_amdgcn_exp2f(-K4 * v);   // e^{-4v}
    const float ap = w * epv, sp = epv;
    const float am = w * emv, sm = emv;
    int bj = (int)floorf((v - LO) * INV_W);
    bj = bj < 0 ? 0 : (bj > K - 1 ? K - 1 : bj);

    // rank captured from the cnt atomic: in-bucket slot, no second atomic pass
    const int rank = atomicAdd(&cnt[bj], 1);
    atomicAdd(&gAp[bj], ap);
    atomicAdd(&gSp[bj], sp);
    atomicAdd(&gAm[bj], am);
    atomicAdd(&gSm[bj], sm);
    __syncthreads();

    // Scans: 5 scans on 5 separate waves, concurrent (waves 5-15 fall through).
    const int wid = tid >> 6;
    if      (wid == 0) scan512_beg(cnt, beg);
    else if (wid == 1) scan512_pre(gAp);
    else if (wid == 2) scan512_pre(gSp);
    else if (wid == 3) scan512_suf(gAm);
    else if (wid == 4) scan512_suf(gSm);
    __syncthreads();

    // Scatter into bucket-grouped order at precomputed slot.
    const int pos = beg[bj] + rank;
    sV[pos] = v; sAp[pos] = ap; sSp[pos] = sp;
    sAm[pos] = am; sSm[pos] = sm;
    __syncthreads();

    // ---- Query: one output element per thread (xq already in register) ----
    int j = (int)floorf((xq - LO) * INV_W);
    j = j < 0 ? 0 : (j > K - 1 ? K - 1 : j);

    const float en  = __builtin_amdgcn_exp2f(-K4 * xq);  // e^{-4x}
    const float epx = __builtin_amdgcn_exp2f( K4 * xq);  // e^{+4x}

    const float Ap = gAp[j];                          // buckets strictly below j
    const float Sp = gSp[j];
    const float Am = (j < K - 1) ? gAm[j + 1] : 0.f;  // buckets strictly above j
    const float Sm = (j < K - 1) ? gSm[j + 1] : 0.f;

    const int s0 = beg[j], s1 = s0 + cnt[j];
    float rAp = 0.f, rSp = 0.f, rAm = 0.f, rSm = 0.f;
    for (int i = s0; i < s1; ++i) {
        const bool le = (sV[i] <= xq);
        rAp += le ? sAp[i] : 0.f;
        rSp += le ? sSp[i] : 0.f;
        rAm += le ? 0.f : sAm[i];
        rSm += le ? 0.f : sSm[i];
    }
    out[o] = (en * (Ap + rAp) + epx * (Am + rAm)) /
             (en * (Sp + rSp) + epx * (Sm + rSm));
}

extern "C" void kernel_launch(void* const* d_in, const int* in_sizes, int n_in,
                              void* d_out, int out_size, void* d_ws, size_t ws_size,
                              hipStream_t stream) {
    const float* x  = (const float*)d_in[0];
    const float* dv = (const float*)d_in[1];
    const float* mv = (const float*)d_in[2];
    float* out = (float*)d_out;

    deformer_one<<<GRID, BLOCK, 0, stream>>>(x, dv, mv, out);
}

// Round 12
// 68.032 us; speedup vs baseline: 1.1034x; 1.0542x over previous
//
#include <hip/hip_runtime.h>
#include <math.h>

// ============================================================================
// FINAL (measured-best, R7 structure): separable-kernel reformulation.
// exp(-4|x-v|) factors as e^{-4x}e^{4v} (v<=x) / e^{4x}e^{-4v} (v>x), so each
// output needs only prefix/suffix sums over value-ordered verts: O(M+N) work
// instead of O(N*M).  Bucket tables (512 buckets over [-4,4]) + exact residual
// over the query's own bucket reproduce the sorted-prefix numerics exactly.
// Suffix tables are accumulated tiny-terms-first (direct reverse scan) --
// NEVER total-minus-prefix (catastrophic cancellation, R3 failed at 1e6 error).
//
// Structure notes (measured):
//  - single self-contained launch; every cross-block sync alternative costs
//    30-110 us on this platform (graph edges R2, coop grid.sync R5, flags R8)
//  - 192 blocks x 1024 threads (1/CU, 16 waves): build is latency-bound;
//    16-wave TLP was -5.9 us vs 256 threads. 2 blocks/CU regressed (+7.5 us).
//  - total = ~40 us mandatory 268 MB ws-poison fill (84% HBM peak, harness)
//    + graph overhead + ~19 us kernel; insensitive to further kernel changes.
// ============================================================================

constexpr int B       = 2;
constexpr int N       = 32768;
constexpr int D       = 3;
constexpr int M_FULL  = 8192;
constexpr int SUBDIV  = 8;
constexpr int M       = M_FULL / SUBDIV;   // 1024 subsampled verts per (b,d)
constexpr int K       = 512;               // value buckets over [-4,4]
constexpr float LO    = -4.0f;
constexpr float INV_W = 64.0f;             // 1 / (8/512)
constexpr int BLOCK   = 1024;              // 16 waves/CU
constexpr int CHUNKS  = N / BLOCK;         // 32 blocks per (b,d) pair
constexpr int GRID    = B * D * CHUNKS;    // 192 blocks -> 1 per CU
constexpr float K4    = 5.770780163555852f; // 4*log2(e): e^{4t} = 2^{K4*t}

// ---- 512-element wave-parallel scans (one wave, lane owns 8 slots) ----
__device__ inline void scan512_pre(float* a) {   // exclusive prefix, small-first
    const int lane = threadIdx.x & 63;
    const int base = lane * 8;
    float xv[8], e[8]; float ls = 0.f;
    #pragma unroll
    for (int t = 0; t < 8; ++t) xv[t] = a[base + t];
    #pragma unroll
    for (int t = 0; t < 8; ++t) { e[t] = ls; ls += xv[t]; }
    float inc = ls;
    #pragma unroll
    for (int off = 1; off < 64; off <<= 1) {
        const float tmp = __shfl_up(inc, off, 64);
        if (lane >= off) inc += tmp;
    }
    const float exoff = inc - ls;
    #pragma unroll
    for (int t = 0; t < 8; ++t) a[base + t] = exoff + e[t];
}

__device__ inline void scan512_suf(float* a) {   // inclusive suffix, small-first
    const int lane = threadIdx.x & 63;
    const int base = lane * 8;
    float xv[8], e[8]; float ls = 0.f;
    #pragma unroll
    for (int t = 0; t < 8; ++t) xv[t] = a[base + t];
    #pragma unroll
    for (int t = 7; t >= 0; --t) { e[t] = ls; ls += xv[t]; }
    float inc = ls;
    #pragma unroll
    for (int off = 1; off < 64; off <<= 1) {
        const float tmp = __shfl_down(inc, off, 64);
        if (lane + off < 64) inc += tmp;
    }
    const float exoff = inc - ls;
    #pragma unroll
    for (int t = 0; t < 8; ++t) a[base + t] = exoff + e[t] + xv[t];
}

__device__ inline void scan512_i(const int* cntA, int* begA, int* curA) {
    const int lane = threadIdx.x & 63;
    const int base = lane * 8;
    int xv[8], e[8]; int ls = 0;
    #pragma unroll
    for (int t = 0; t < 8; ++t) xv[t] = cntA[base + t];
    #pragma unroll
    for (int t = 0; t < 8; ++t) { e[t] = ls; ls += xv[t]; }
    int inc = ls;
    #pragma unroll
    for (int off = 1; off < 64; off <<= 1) {
        const int tmp = __shfl_up(inc, off, 64);
        if (lane >= off) inc += tmp;
    }
    const int exoff = inc - ls;
    #pragma unroll
    for (int t = 0; t < 8; ++t) {
        begA[base + t] = exoff + e[t];
        curA[base + t] = exoff + e[t];
    }
}

__global__ __launch_bounds__(BLOCK) void deformer_one(
    const float* __restrict__ x,
    const float* __restrict__ dverts,
    const float* __restrict__ mverts,
    float* __restrict__ out)
{
    // bucket-grouped per-vert tuples
    __shared__ float sV[M], sAp[M], sSp[M], sAm[M], sSm[M];      // 20 KB
    // per-bucket aggregates; after scans: Ap/Sp = exclusive prefix,
    // Am/Sm = inclusive suffix (both accumulated tiny-terms-first).
    __shared__ float gAp[K], gSp[K], gAm[K], gSm[K];             // 8 KB
    __shared__ int   cnt[K], beg[K], cur[K];                      // 6 KB

    const int tid = threadIdx.x;
    const int p = blockIdx.x >> 5;    // pair 0..5
    const int c = blockIdx.x & 31;    // chunk within pair
    const int b = p / 3, d = p % 3;

    if (tid < K) {
        cnt[tid] = 0; gAp[tid] = 0.f; gSp[tid] = 0.f; gAm[tid] = 0.f; gSm[tid] = 0.f;
    }
    __syncthreads();

    // ---- Build: one vert per thread (M == BLOCK) ----
    const int g = (b * M_FULL + tid * SUBDIV) * D + d;
    const float v = dverts[g];
    const float w = mverts[g];
    const float epv = __builtin_amdgcn_exp2f( K4 * v);   // e^{4v}
    const float emv = __builtin_amdgcn_exp2f(-K4 * v);   // e^{-4v}
    const float ap = w * epv, sp = epv;
    const float am = w * emv, sm = emv;
    int bj = (int)floorf((v - LO) * INV_W);
    bj = bj < 0 ? 0 : (bj > K - 1 ? K - 1 : bj);
    atomicAdd(&cnt[bj], 1);
    atomicAdd(&gAp[bj], ap);
    atomicAdd(&gSp[bj], sp);
    atomicAdd(&gAm[bj], am);
    atomicAdd(&gSm[bj], sm);
    __syncthreads();

    // Scans: 5 scans on 5 separate waves, concurrent (waves 5-15 fall through).
    const int wid = tid >> 6;
    if      (wid == 0) scan512_i(cnt, beg, cur);
    else if (wid == 1) scan512_pre(gAp);
    else if (wid == 2) scan512_pre(gSp);
    else if (wid == 3) scan512_suf(gAm);
    else if (wid == 4) scan512_suf(gSm);
    __syncthreads();

    // Counting scatter into bucket-grouped order.
    const int pos = atomicAdd(&cur[bj], 1);
    sV[pos] = v; sAp[pos] = ap; sSp[pos] = sp;
    sAm[pos] = am; sSm[pos] = sm;
    __syncthreads();

    // ---- Query: one output element per thread ----
    const int n = c * BLOCK + tid;
    const int o = (b * N + n) * D + d;
    const float xq = x[o];

    int j = (int)floorf((xq - LO) * INV_W);
    j = j < 0 ? 0 : (j > K - 1 ? K - 1 : j);

    const float en  = __builtin_amdgcn_exp2f(-K4 * xq);  // e^{-4x}
    const float epx = __builtin_amdgcn_exp2f( K4 * xq);  // e^{+4x}

    const float Ap = gAp[j];                          // buckets strictly below j
    const float Sp = gSp[j];
    const float Am = (j < K - 1) ? gAm[j + 1] : 0.f;  // buckets strictly above j
    const float Sm = (j < K - 1) ? gSm[j + 1] : 0.f;

    const int s0 = beg[j], s1 = s0 + cnt[j];
    float rAp = 0.f, rSp = 0.f, rAm = 0.f, rSm = 0.f;
    for (int i = s0; i < s1; ++i) {
        const bool le = (sV[i] <= xq);
        rAp += le ? sAp[i] : 0.f;
        rSp += le ? sSp[i] : 0.f;
        rAm += le ? 0.f : sAm[i];
        rSm += le ? 0.f : sSm[i];
    }
    out[o] = (en * (Ap + rAp) + epx * (Am + rAm)) /
             (en * (Sp + rSp) + epx * (Sm + rSm));
}

extern "C" void kernel_launch(void* const* d_in, const int* in_sizes, int n_in,
                              void* d_out, int out_size, void* d_ws, size_t ws_size,
                              hipStream_t stream) {
    const float* x  = (const float*)d_in[0];
    const float* dv = (const float*)d_in[1];
    const float* mv = (const float*)d_in[2];
    float* out = (float*)d_out;

    deformer_one<<<GRID, BLOCK, 0, stream>>>(x, dv, mv, out);
}